// Round 1
// baseline (1360.924 us; speedup 1.0000x reference)
//
#include <hip/hip_runtime.h>

#define N_NODES 100000
#define N_EDGES 1600000
#define IN_DIM 128
#define HID_DIM 32

// h[N,32] = x[N,128] @ W[128,32]; 8 rows per block, 256 threads.
__global__ __launch_bounds__(256) void mm128_32(const float* __restrict__ x,
                                                const float* __restrict__ W,
                                                float* __restrict__ h) {
    __shared__ float Ws[IN_DIM * HID_DIM];   // 16 KB
    __shared__ float xs[8 * IN_DIM];         // 4 KB
    const int tid = threadIdx.x;

    // Load W1 (4096 floats = 1024 float4) cooperatively.
    const float4* W4 = (const float4*)W;
    float4* Ws4 = (float4*)Ws;
#pragma unroll
    for (int i = 0; i < 4; ++i) Ws4[tid + i * 256] = W4[tid + i * 256];

    // Load 8 x-rows (1024 floats = 256 float4).
    const int row0 = blockIdx.x * 8;
    const float4* x4 = (const float4*)(x + (size_t)row0 * IN_DIM);
    ((float4*)xs)[tid] = x4[tid];
    __syncthreads();

    const int r = tid >> 5, c = tid & 31;
    const float* xr = xs + r * IN_DIM;
    float acc = 0.f;
#pragma unroll 16
    for (int k = 0; k < IN_DIM; ++k) acc += xr[k] * Ws[k * HID_DIM + c];
    h[(size_t)(row0 + r) * HID_DIM + c] = acc;
}

// h[N,32] = a[N,32] @ W[32,32]; 8 rows per block, 256 threads.
__global__ __launch_bounds__(256) void mm32_32(const float* __restrict__ a,
                                               const float* __restrict__ W,
                                               float* __restrict__ h) {
    __shared__ float Ws[HID_DIM * HID_DIM];  // 4 KB
    __shared__ float as[8 * HID_DIM];        // 1 KB
    const int tid = threadIdx.x;

    ((float4*)Ws)[tid] = ((const float4*)W)[tid];        // 1024 floats
    const int row0 = blockIdx.x * 8;
    as[tid] = a[(size_t)row0 * HID_DIM + tid];           // 256 floats
    __syncthreads();

    const int r = tid >> 5, c = tid & 31;
    float acc = 0.f;
#pragma unroll
    for (int k = 0; k < HID_DIM; ++k) acc += as[r * HID_DIM + k] * Ws[k * HID_DIM + c];
    h[(size_t)(row0 + r) * HID_DIM + c] = acc;
}

// out[dst] += w * h[src], 32 floats per edge. One thread per (edge, float4).
__global__ __launch_bounds__(256) void scatter32(const int* __restrict__ ei,
                                                 const float* __restrict__ ew,
                                                 const float* __restrict__ h,
                                                 float* __restrict__ out) {
    const int gid = blockIdx.x * 256 + threadIdx.x;
    const int e = gid >> 3;
    const int q = gid & 7;
    const int src = ei[e];
    const int dst = ei[N_EDGES + e];
    const float w = ew[e];
    const float4 v = ((const float4*)h)[(size_t)src * 8 + q];
    float* o = out + (size_t)dst * HID_DIM + q * 4;
    atomicAdd(o + 0, v.x * w);
    atomicAdd(o + 1, v.y * w);
    atomicAdd(o + 2, v.z * w);
    atomicAdd(o + 3, v.w * w);
}

extern "C" void kernel_launch(void* const* d_in, const int* in_sizes, int n_in,
                              void* d_out, int out_size, void* d_ws, size_t ws_size,
                              hipStream_t stream) {
    const float* x  = (const float*)d_in[0];
    const float* W1 = (const float*)d_in[1];
    const float* W2 = (const float*)d_in[2];
    const float* ew = (const float*)d_in[3];
    const int*   ei = (const int*)d_in[4];
    float* out = (float*)d_out;

    float* h  = (float*)d_ws;                      // N*32 fp32 (h1, later h2)
    float* a1 = h + (size_t)N_NODES * HID_DIM;     // N*32 fp32 (layer-1 aggregate)

    const size_t feat_bytes = (size_t)N_NODES * HID_DIM * sizeof(float);

    // Layer 1
    hipMemsetAsync(a1, 0, feat_bytes, stream);
    mm128_32<<<N_NODES / 8, 256, 0, stream>>>(x, W1, h);
    scatter32<<<(N_EDGES * 8) / 256, 256, 0, stream>>>(ei, ew, h, a1);

    // Layer 2
    mm32_32<<<N_NODES / 8, 256, 0, stream>>>(a1, W2, h);
    hipMemsetAsync(out, 0, feat_bytes, stream);
    scatter32<<<(N_EDGES * 8) / 256, 256, 0, stream>>>(ei, ew, h, out);
}

// Round 2
// 585.906 us; speedup vs baseline: 2.3228x; 2.3228x over previous
//
#include <hip/hip_runtime.h>

#define N_NODES 100000
#define N_EDGES 1600000
#define IN_DIM 128
#define HID_DIM 32

// ---------- dense matmuls ----------

// h[N,32] = x[N,128] @ W[128,32]; 8 rows per block, 256 threads.
__global__ __launch_bounds__(256) void mm128_32(const float* __restrict__ x,
                                                const float* __restrict__ W,
                                                float* __restrict__ h) {
    __shared__ float Ws[IN_DIM * HID_DIM];   // 16 KB
    __shared__ float xs[8 * IN_DIM];         // 4 KB
    const int tid = threadIdx.x;

    const float4* W4 = (const float4*)W;
    float4* Ws4 = (float4*)Ws;
#pragma unroll
    for (int i = 0; i < 4; ++i) Ws4[tid + i * 256] = W4[tid + i * 256];

    const int row0 = blockIdx.x * 8;
    const float4* x4 = (const float4*)(x + (size_t)row0 * IN_DIM);
    ((float4*)xs)[tid] = x4[tid];
    __syncthreads();

    const int r = tid >> 5, c = tid & 31;
    const float* xr = xs + r * IN_DIM;
    float acc = 0.f;
#pragma unroll 16
    for (int k = 0; k < IN_DIM; ++k) acc += xr[k] * Ws[k * HID_DIM + c];
    h[(size_t)(row0 + r) * HID_DIM + c] = acc;
}

// h[N,32] = a[N,32] @ W[32,32]; 8 rows per block, 256 threads.
__global__ __launch_bounds__(256) void mm32_32(const float* __restrict__ a,
                                               const float* __restrict__ W,
                                               float* __restrict__ h) {
    __shared__ float Ws[HID_DIM * HID_DIM];  // 4 KB
    __shared__ float as[8 * HID_DIM];        // 1 KB
    const int tid = threadIdx.x;

    ((float4*)Ws)[tid] = ((const float4*)W)[tid];
    const int row0 = blockIdx.x * 8;
    as[tid] = a[(size_t)row0 * HID_DIM + tid];
    __syncthreads();

    const int r = tid >> 5, c = tid & 31;
    float acc = 0.f;
#pragma unroll
    for (int k = 0; k < HID_DIM; ++k) acc += as[r * HID_DIM + k] * Ws[k * HID_DIM + c];
    h[(size_t)(row0 + r) * HID_DIM + c] = acc;
}

// ---------- CSR-by-dst construction ----------

__global__ __launch_bounds__(256) void hist_kernel(const int* __restrict__ ei,
                                                   int* __restrict__ deg) {
    const int e = blockIdx.x * 256 + threadIdx.x;
    if (e < N_EDGES) atomicAdd(&deg[ei[N_EDGES + e]], 1);
}

// Single-block exclusive scan of deg[0..N) -> offs[0..N], plus cursor copy.
__global__ __launch_bounds__(1024) void scan_kernel(const int* __restrict__ deg,
                                                    int* __restrict__ offs,
                                                    int* __restrict__ cursor) {
    __shared__ int part[1024];
    const int t = threadIdx.x;
    const int chunk = (N_NODES + 1023) / 1024;  // 98
    int lo = t * chunk;
    int hi = lo + chunk;
    if (lo > N_NODES) lo = N_NODES;
    if (hi > N_NODES) hi = N_NODES;

    int s = 0;
    for (int i = lo; i < hi; ++i) s += deg[i];
    part[t] = s;
    __syncthreads();

    // Hillis-Steele inclusive scan over the 1024 partials.
    for (int off = 1; off < 1024; off <<= 1) {
        int tmp = 0;
        if (t >= off) tmp = part[t - off];
        __syncthreads();
        part[t] += tmp;
        __syncthreads();
    }

    int run = part[t] - s;  // exclusive base for this chunk
    for (int i = lo; i < hi; ++i) {
        const int d = deg[i];
        offs[i] = run;
        cursor[i] = run;
        run += d;
    }
    if (t == 1023) offs[N_NODES] = part[1023];
}

__global__ __launch_bounds__(256) void reorder_kernel(const int* __restrict__ ei,
                                                      const float* __restrict__ ew,
                                                      int* __restrict__ cursor,
                                                      int* __restrict__ csrc,
                                                      float* __restrict__ cw) {
    const int e = blockIdx.x * 256 + threadIdx.x;
    if (e < N_EDGES) {
        const int dst = ei[N_EDGES + e];
        const int pos = atomicAdd(&cursor[dst], 1);
        csrc[pos] = ei[e];
        cw[pos] = ew[e];
    }
}

// ---------- gather aggregation: out[n,c] = sum_{e in CSR[n]} w_e * h[src_e, c] ----------

__global__ __launch_bounds__(256) void gather_agg(const int* __restrict__ offs,
                                                  const int* __restrict__ csrc,
                                                  const float* __restrict__ cw,
                                                  const float* __restrict__ h,
                                                  float* __restrict__ out) {
    const int tid = threadIdx.x;
    const int node = blockIdx.x * 8 + (tid >> 5);
    const int c = tid & 31;
    if (node >= N_NODES) return;

    int i = offs[node];
    const int end = offs[node + 1];
    float acc = 0.f;
    for (; i + 1 < end; i += 2) {
        const int s0 = csrc[i], s1 = csrc[i + 1];
        const float w0 = cw[i], w1 = cw[i + 1];
        acc += w0 * h[(size_t)s0 * HID_DIM + c];
        acc += w1 * h[(size_t)s1 * HID_DIM + c];
    }
    if (i < end) acc += cw[i] * h[(size_t)csrc[i] * HID_DIM + c];
    out[(size_t)node * HID_DIM + c] = acc;
}

extern "C" void kernel_launch(void* const* d_in, const int* in_sizes, int n_in,
                              void* d_out, int out_size, void* d_ws, size_t ws_size,
                              hipStream_t stream) {
    const float* x  = (const float*)d_in[0];
    const float* W1 = (const float*)d_in[1];
    const float* W2 = (const float*)d_in[2];
    const float* ew = (const float*)d_in[3];
    const int*   ei = (const int*)d_in[4];
    float* out = (float*)d_out;

    // workspace layout (~26.8 MB)
    float* h      = (float*)d_ws;                      // N*32 fp32
    int*   csrc   = (int*)(h + (size_t)N_NODES * HID_DIM);  // E ints
    float* cw     = (float*)(csrc + N_EDGES);          // E floats
    int*   deg    = (int*)(cw + N_EDGES);              // N ints
    int*   offs   = deg + N_NODES;                     // N+1 ints
    int*   cursor = offs + N_NODES + 1;                // N ints

    // ---- CSR build (shared by both layers) ----
    hipMemsetAsync(deg, 0, N_NODES * sizeof(int), stream);
    hist_kernel<<<(N_EDGES + 255) / 256, 256, 0, stream>>>(ei, deg);
    scan_kernel<<<1, 1024, 0, stream>>>(deg, offs, cursor);
    reorder_kernel<<<(N_EDGES + 255) / 256, 256, 0, stream>>>(ei, ew, cursor, csrc, cw);

    // ---- Layer 1: h = x@W1 ; a1 = gather(h)  (a1 staged in d_out) ----
    mm128_32<<<N_NODES / 8, 256, 0, stream>>>(x, W1, h);
    gather_agg<<<(N_NODES + 7) / 8, 256, 0, stream>>>(offs, csrc, cw, h, out);

    // ---- Layer 2: h = a1@W2 ; out = gather(h) ----
    mm32_32<<<N_NODES / 8, 256, 0, stream>>>(out, W2, h);
    gather_agg<<<(N_NODES + 7) / 8, 256, 0, stream>>>(offs, csrc, cw, h, out);
}

// Round 3
// 354.460 us; speedup vs baseline: 3.8394x; 1.6530x over previous
//
#include <hip/hip_runtime.h>

#define N_NODES 100000
#define N_EDGES 1600000
#define IN_DIM 128
#define HID_DIM 32
#define NB_SCAN ((N_NODES + 255) / 256)   // 391 scan blocks

// ---------- dense matmuls ----------

__global__ __launch_bounds__(256) void mm128_32(const float* __restrict__ x,
                                                const float* __restrict__ W,
                                                float* __restrict__ h) {
    __shared__ float Ws[IN_DIM * HID_DIM];   // 16 KB
    __shared__ float xs[8 * IN_DIM];         // 4 KB
    const int tid = threadIdx.x;

    const float4* W4 = (const float4*)W;
    float4* Ws4 = (float4*)Ws;
#pragma unroll
    for (int i = 0; i < 4; ++i) Ws4[tid + i * 256] = W4[tid + i * 256];

    const int row0 = blockIdx.x * 8;
    const float4* x4 = (const float4*)(x + (size_t)row0 * IN_DIM);
    ((float4*)xs)[tid] = x4[tid];
    __syncthreads();

    const int r = tid >> 5, c = tid & 31;
    const float* xr = xs + r * IN_DIM;
    float acc = 0.f;
#pragma unroll 16
    for (int k = 0; k < IN_DIM; ++k) acc += xr[k] * Ws[k * HID_DIM + c];
    h[(size_t)(row0 + r) * HID_DIM + c] = acc;
}

__global__ __launch_bounds__(256) void mm32_32(const float* __restrict__ a,
                                               const float* __restrict__ W,
                                               float* __restrict__ h) {
    __shared__ float Ws[HID_DIM * HID_DIM];  // 4 KB
    __shared__ float as[8 * HID_DIM];        // 1 KB
    const int tid = threadIdx.x;

    ((float4*)Ws)[tid] = ((const float4*)W)[tid];
    const int row0 = blockIdx.x * 8;
    as[tid] = a[(size_t)row0 * HID_DIM + tid];
    __syncthreads();

    const int r = tid >> 5, c = tid & 31;
    float acc = 0.f;
#pragma unroll
    for (int k = 0; k < HID_DIM; ++k) acc += as[r * HID_DIM + k] * Ws[k * HID_DIM + c];
    h[(size_t)(row0 + r) * HID_DIM + c] = acc;
}

// ---------- CSR-by-dst construction ----------

__global__ __launch_bounds__(256) void hist_kernel(const int* __restrict__ ei,
                                                   int* __restrict__ deg) {
    const int e = blockIdx.x * 256 + threadIdx.x;
    if (e < N_EDGES) atomicAdd(&deg[ei[N_EDGES + e]], 1);
}

// Phase 1: block-local exclusive scan of deg -> offs (local), block total -> part[b].
__global__ __launch_bounds__(256) void scan_local(const int* __restrict__ deg,
                                                  int* __restrict__ offs,
                                                  int* __restrict__ part) {
    const int t = threadIdx.x;
    const int i = blockIdx.x * 256 + t;
    const int lane = t & 63;
    const int wave = t >> 6;

    int v = (i < N_NODES) ? deg[i] : 0;

    // wave-inclusive scan over 64 lanes
    int incl = v;
#pragma unroll
    for (int off = 1; off < 64; off <<= 1) {
        int n = __shfl_up(incl, off, 64);
        if (lane >= off) incl += n;
    }

    __shared__ int wsum[4];
    if (lane == 63) wsum[wave] = incl;
    __syncthreads();

    int base = 0;
#pragma unroll
    for (int wv = 0; wv < 4; ++wv)
        if (wv < wave) base += wsum[wv];

    if (i < N_NODES) offs[i] = base + incl - v;   // block-local exclusive
    if (t == 255) part[blockIdx.x] = base + incl; // block total
}

// Phase 2: scan the 391 block totals (exclusive), write grand total to offs[N].
__global__ __launch_bounds__(512) void scan_part(int* __restrict__ part,
                                                 int* __restrict__ offs) {
    __shared__ int s[512];
    const int t = threadIdx.x;
    const int v = (t < NB_SCAN) ? part[t] : 0;
    s[t] = v;
    __syncthreads();
    for (int off = 1; off < 512; off <<= 1) {
        int tmp = (t >= off) ? s[t - off] : 0;
        __syncthreads();
        s[t] += tmp;
        __syncthreads();
    }
    if (t < NB_SCAN) part[t] = s[t] - v;  // exclusive base per block
    if (t == 511) offs[N_NODES] = s[511];
}

// Phase 3: add block base; mirror into cursor.
__global__ __launch_bounds__(256) void scan_add(int* __restrict__ offs,
                                                const int* __restrict__ part,
                                                int* __restrict__ cursor) {
    const int i = blockIdx.x * 256 + threadIdx.x;
    if (i < N_NODES) {
        const int o = offs[i] + part[blockIdx.x];
        offs[i] = o;
        cursor[i] = o;
    }
}

__global__ __launch_bounds__(256) void reorder_kernel(const int* __restrict__ ei,
                                                      const float* __restrict__ ew,
                                                      int* __restrict__ cursor,
                                                      int* __restrict__ csrc,
                                                      float* __restrict__ cw) {
    const int e = blockIdx.x * 256 + threadIdx.x;
    if (e < N_EDGES) {
        const int dst = ei[N_EDGES + e];
        const int pos = atomicAdd(&cursor[dst], 1);
        csrc[pos] = ei[e];
        cw[pos] = ew[e];
    }
}

// ---------- gather aggregation ----------

__global__ __launch_bounds__(256) void gather_agg(const int* __restrict__ offs,
                                                  const int* __restrict__ csrc,
                                                  const float* __restrict__ cw,
                                                  const float* __restrict__ h,
                                                  float* __restrict__ out) {
    const int tid = threadIdx.x;
    const int node = blockIdx.x * 8 + (tid >> 5);
    const int c = tid & 31;
    if (node >= N_NODES) return;

    int i = offs[node];
    const int end = offs[node + 1];
    float acc = 0.f;
    for (; i + 1 < end; i += 2) {
        const int s0 = csrc[i], s1 = csrc[i + 1];
        const float w0 = cw[i], w1 = cw[i + 1];
        acc += w0 * h[(size_t)s0 * HID_DIM + c];
        acc += w1 * h[(size_t)s1 * HID_DIM + c];
    }
    if (i < end) acc += cw[i] * h[(size_t)csrc[i] * HID_DIM + c];
    out[(size_t)node * HID_DIM + c] = acc;
}

extern "C" void kernel_launch(void* const* d_in, const int* in_sizes, int n_in,
                              void* d_out, int out_size, void* d_ws, size_t ws_size,
                              hipStream_t stream) {
    const float* x  = (const float*)d_in[0];
    const float* W1 = (const float*)d_in[1];
    const float* W2 = (const float*)d_in[2];
    const float* ew = (const float*)d_in[3];
    const int*   ei = (const int*)d_in[4];
    float* out = (float*)d_out;

    // workspace layout (~26.8 MB)
    float* h      = (float*)d_ws;                           // N*32 fp32
    int*   csrc   = (int*)(h + (size_t)N_NODES * HID_DIM);  // E ints
    float* cw     = (float*)(csrc + N_EDGES);               // E floats
    int*   deg    = (int*)(cw + N_EDGES);                   // N ints
    int*   offs   = deg + N_NODES;                          // N+1 ints
    int*   cursor = offs + N_NODES + 1;                     // N ints
    int*   part   = cursor + N_NODES;                       // NB_SCAN ints

    // ---- CSR build (shared by both layers) ----
    hipMemsetAsync(deg, 0, N_NODES * sizeof(int), stream);
    hist_kernel<<<(N_EDGES + 255) / 256, 256, 0, stream>>>(ei, deg);
    scan_local<<<NB_SCAN, 256, 0, stream>>>(deg, offs, part);
    scan_part<<<1, 512, 0, stream>>>(part, offs);
    scan_add<<<NB_SCAN, 256, 0, stream>>>(offs, part, cursor);
    reorder_kernel<<<(N_EDGES + 255) / 256, 256, 0, stream>>>(ei, ew, cursor, csrc, cw);

    // ---- Layer 1: h = x@W1 ; a1 = gather(h)  (a1 staged in d_out) ----
    mm128_32<<<N_NODES / 8, 256, 0, stream>>>(x, W1, h);
    gather_agg<<<(N_NODES + 7) / 8, 256, 0, stream>>>(offs, csrc, cw, h, out);

    // ---- Layer 2: h = a1@W2 ; out = gather(h) ----
    mm32_32<<<N_NODES / 8, 256, 0, stream>>>(out, W2, h);
    gather_agg<<<(N_NODES + 7) / 8, 256, 0, stream>>>(offs, csrc, cw, h, out);
}

// Round 4
// 241.029 us; speedup vs baseline: 5.6463x; 1.4706x over previous
//
#include <hip/hip_runtime.h>

#define N_NODES 100000
#define N_EDGES 1600000
#define IN_DIM 128
#define HID_DIM 32

#define NPB 256                                   // nodes per bucket
#define BSHIFT 8
#define NBUCK ((N_NODES + NPB - 1) / NPB)         // 391
#define EPB 8192                                  // edges per block (hist/phaseA)
#define NBLK_E ((N_EDGES + EPB - 1) / EPB)        // 196

// ---------- dense matmuls ----------

__global__ __launch_bounds__(256) void mm128_32(const float* __restrict__ x,
                                                const float* __restrict__ W,
                                                float* __restrict__ h) {
    __shared__ float Ws[IN_DIM * HID_DIM];   // 16 KB
    __shared__ float xs[8 * IN_DIM];         // 4 KB
    const int tid = threadIdx.x;

    const float4* W4 = (const float4*)W;
    float4* Ws4 = (float4*)Ws;
#pragma unroll
    for (int i = 0; i < 4; ++i) Ws4[tid + i * 256] = W4[tid + i * 256];

    const int row0 = blockIdx.x * 8;
    const float4* x4 = (const float4*)(x + (size_t)row0 * IN_DIM);
    ((float4*)xs)[tid] = x4[tid];
    __syncthreads();

    const int r = tid >> 5, c = tid & 31;
    const float* xr = xs + r * IN_DIM;
    float acc = 0.f;
#pragma unroll 16
    for (int k = 0; k < IN_DIM; ++k) acc += xr[k] * Ws[k * HID_DIM + c];
    h[(size_t)(row0 + r) * HID_DIM + c] = acc;
}

__global__ __launch_bounds__(256) void mm32_32(const float* __restrict__ a,
                                               const float* __restrict__ W,
                                               float* __restrict__ h) {
    __shared__ float Ws[HID_DIM * HID_DIM];  // 4 KB
    __shared__ float as[8 * HID_DIM];        // 1 KB
    const int tid = threadIdx.x;

    ((float4*)Ws)[tid] = ((const float4*)W)[tid];
    const int row0 = blockIdx.x * 8;
    as[tid] = a[(size_t)row0 * HID_DIM + tid];
    __syncthreads();

    const int r = tid >> 5, c = tid & 31;
    float acc = 0.f;
#pragma unroll
    for (int k = 0; k < HID_DIM; ++k) acc += as[r * HID_DIM + k] * Ws[k * HID_DIM + c];
    h[(size_t)(row0 + r) * HID_DIM + c] = acc;
}

// ---------- bucketed CSR-by-dst construction ----------

// Per-block LDS histogram of dst buckets, flushed with one atomic per bucket.
__global__ __launch_bounds__(256) void bucket_hist(const int* __restrict__ ei,
                                                   int* __restrict__ bhist) {
    __shared__ int lh[NBUCK];
    for (int j = threadIdx.x; j < NBUCK; j += 256) lh[j] = 0;
    __syncthreads();
    const int e0 = blockIdx.x * EPB;
    const int e1 = min(N_EDGES, e0 + EPB);
    for (int e = e0 + threadIdx.x; e < e1; e += 256)
        atomicAdd(&lh[ei[N_EDGES + e] >> BSHIFT], 1);
    __syncthreads();
    for (int j = threadIdx.x; j < NBUCK; j += 256)
        if (lh[j]) atomicAdd(&bhist[j], lh[j]);
}

// Exclusive scan of 391 bucket counts; init bucket cursors; offs[N]=E.
__global__ __launch_bounds__(512) void bucket_scan(const int* __restrict__ bhist,
                                                   int* __restrict__ boffs,
                                                   int* __restrict__ bcur,
                                                   int* __restrict__ offs) {
    __shared__ int s[512];
    const int t = threadIdx.x;
    const int v = (t < NBUCK) ? bhist[t] : 0;
    s[t] = v;
    __syncthreads();
    for (int off = 1; off < 512; off <<= 1) {
        int tmp = (t >= off) ? s[t - off] : 0;
        __syncthreads();
        s[t] += tmp;
        __syncthreads();
    }
    if (t < NBUCK) { const int ex = s[t] - v; boffs[t] = ex; bcur[t] = ex; }
    if (t == 511) { boffs[NBUCK] = s[511]; offs[N_NODES] = s[511]; }
}

// Scatter edges into bucket-segmented pairA with per-block range reservation.
// pair.x = src | (dst&255)<<17 ; pair.y = weight bits.
__global__ __launch_bounds__(256) void phaseA(const int* __restrict__ ei,
                                              const float* __restrict__ ew,
                                              int* __restrict__ bcur,
                                              int2* __restrict__ pairA) {
    __shared__ int lh[NBUCK];
    __shared__ int lbase[NBUCK];
    __shared__ int lc[NBUCK];
    for (int j = threadIdx.x; j < NBUCK; j += 256) { lh[j] = 0; lc[j] = 0; }
    __syncthreads();
    const int e0 = blockIdx.x * EPB;
    const int e1 = min(N_EDGES, e0 + EPB);
    for (int e = e0 + threadIdx.x; e < e1; e += 256)
        atomicAdd(&lh[ei[N_EDGES + e] >> BSHIFT], 1);
    __syncthreads();
    for (int j = threadIdx.x; j < NBUCK; j += 256)
        if (lh[j]) lbase[j] = atomicAdd(&bcur[j], lh[j]);
    __syncthreads();
    for (int e = e0 + threadIdx.x; e < e1; e += 256) {
        const int dst = ei[N_EDGES + e];
        const int b = dst >> BSHIFT;
        const int pos = lbase[b] + atomicAdd(&lc[b], 1);
        pairA[pos] = make_int2(ei[e] | ((dst & (NPB - 1)) << 17),
                               __float_as_int(ew[e]));
    }
}

// One block per bucket: local node histogram + scan -> offs; place pairs in CSR order.
__global__ __launch_bounds__(256) void phaseB(const int* __restrict__ boffs,
                                              const int2* __restrict__ pairA,
                                              int2* __restrict__ csr,
                                              int* __restrict__ offs) {
    __shared__ int lh[NPB];   // hist, then cursor
    __shared__ int lx[NPB];   // scan
    const int b = blockIdx.x;
    const int base = boffs[b];
    const int cnt = boffs[b + 1] - base;
    const int t = threadIdx.x;

    lh[t] = 0;
    __syncthreads();
    for (int i = t; i < cnt; i += 256)
        atomicAdd(&lh[(pairA[base + i].x >> 17) & (NPB - 1)], 1);
    __syncthreads();

    const int v = lh[t];
    lx[t] = v;
    __syncthreads();
    for (int off = 1; off < NPB; off <<= 1) {
        int tmp = (t >= off) ? lx[t - off] : 0;
        __syncthreads();
        lx[t] += tmp;
        __syncthreads();
    }
    const int excl = lx[t] - v;
    lh[t] = excl;                           // becomes cursor
    const int node = (b << BSHIFT) + t;
    if (node < N_NODES) offs[node] = base + excl;
    __syncthreads();

    for (int i = t; i < cnt; i += 256) {
        const int2 p = pairA[base + i];
        const int dl = (p.x >> 17) & (NPB - 1);
        const int pos = atomicAdd(&lh[dl], 1);
        csr[base + pos] = make_int2(p.x & 0x1FFFF, p.y);
    }
}

// ---------- gather aggregation ----------

__global__ __launch_bounds__(256) void gather_agg(const int* __restrict__ offs,
                                                  const int2* __restrict__ csr,
                                                  const float* __restrict__ h,
                                                  float* __restrict__ out) {
    const int tid = threadIdx.x;
    const int node = blockIdx.x * 8 + (tid >> 5);
    const int c = tid & 31;
    if (node >= N_NODES) return;

    int i = offs[node];
    const int end = offs[node + 1];
    float acc = 0.f;
    for (; i + 1 < end; i += 2) {
        const int2 p0 = csr[i], p1 = csr[i + 1];
        acc += __int_as_float(p0.y) * h[(size_t)p0.x * HID_DIM + c];
        acc += __int_as_float(p1.y) * h[(size_t)p1.x * HID_DIM + c];
    }
    if (i < end) {
        const int2 p = csr[i];
        acc += __int_as_float(p.y) * h[(size_t)p.x * HID_DIM + c];
    }
    out[(size_t)node * HID_DIM + c] = acc;
}

extern "C" void kernel_launch(void* const* d_in, const int* in_sizes, int n_in,
                              void* d_out, int out_size, void* d_ws, size_t ws_size,
                              hipStream_t stream) {
    const float* x  = (const float*)d_in[0];
    const float* W1 = (const float*)d_in[1];
    const float* W2 = (const float*)d_in[2];
    const float* ew = (const float*)d_in[3];
    const int*   ei = (const int*)d_in[4];
    float* out = (float*)d_out;

    // workspace layout (~26.5 MB); pairA aliases h (phaseB finishes before mm128 writes h)
    float* h     = (float*)d_ws;                            // N*32 fp32 (12.8 MB)
    int2*  pairA = (int2*)d_ws;                             // E int2 (12.8 MB) — aliased
    int2*  csr   = (int2*)((char*)d_ws + (size_t)N_EDGES * 8);  // E int2 (12.8 MB)
    int*   offs  = (int*)(csr + N_EDGES);                   // N+1 ints
    int*   bhist = offs + N_NODES + 1;                      // NBUCK
    int*   boffs = bhist + NBUCK;                           // NBUCK+1
    int*   bcur  = boffs + NBUCK + 1;                       // NBUCK

    // ---- CSR build (shared by both layers) ----
    hipMemsetAsync(bhist, 0, NBUCK * sizeof(int), stream);
    bucket_hist<<<NBLK_E, 256, 0, stream>>>(ei, bhist);
    bucket_scan<<<1, 512, 0, stream>>>(bhist, boffs, bcur, offs);
    phaseA<<<NBLK_E, 256, 0, stream>>>(ei, ew, bcur, pairA);
    phaseB<<<NBUCK, 256, 0, stream>>>(boffs, pairA, csr, offs);

    // ---- Layer 1: h = x@W1 ; a1 = gather(h)  (a1 staged in d_out) ----
    mm128_32<<<N_NODES / 8, 256, 0, stream>>>(x, W1, h);
    gather_agg<<<(N_NODES + 7) / 8, 256, 0, stream>>>(offs, csr, h, out);

    // ---- Layer 2: h = a1@W2 ; out = gather(h) ----
    mm32_32<<<N_NODES / 8, 256, 0, stream>>>(out, W2, h);
    gather_agg<<<(N_NODES + 7) / 8, 256, 0, stream>>>(offs, csr, h, out);
}